// Round 1
// baseline (347.054 us; speedup 1.0000x reference)
//
#include <hip/hip_runtime.h>

// FCE loss: per-row softmax(pred/T) over C=1000 classes, then
// loss[j] = -log(p_t + eps) - w_t * sum_{c != t} log(1 - p_c + eps)
//
// Layout: one 64-lane wave per row, 16 f32/lane held in registers so the
// 3 logical passes (max, sum-exp, sum-log) read HBM exactly once.
// Row stride = 1000 f32 = 4000 B (16B aligned) -> float4 loads coalesce.

#define C_CLASSES 1000
#define TEMP_INV  0.25f
#define FCE_EPS   1e-7f

__global__ __launch_bounds__(256) void fce_kernel(
    const float* __restrict__ pred,
    const float* __restrict__ weight,
    const int*   __restrict__ teacher,
    float*       __restrict__ out,
    int B)
{
    const int lane = threadIdx.x & 63;
    const int wave = threadIdx.x >> 6;
    const int row  = blockIdx.x * 4 + wave;
    if (row >= B) return;

    const float* rp = pred + (size_t)row * C_CLASSES;

    // ---- load entire row into registers: 4 x float4 per lane ----
    float v[16];
#pragma unroll
    for (int it = 0; it < 4; ++it) {
        const int idx4 = it * 64 + lane;           // which float4 of the row
        if (idx4 < C_CLASSES / 4) {                // 250 float4s cover 1000 elems
            float4 f = ((const float4*)rp)[idx4];
            v[it*4+0] = f.x; v[it*4+1] = f.y; v[it*4+2] = f.z; v[it*4+3] = f.w;
        } else {
            // padding: large-negative so exp() -> 0, excluded from S by idx check
            v[it*4+0] = v[it*4+1] = v[it*4+2] = v[it*4+3] = -1e30f;
        }
    }

    // ---- pass 1: row max (wave butterfly reduce) ----
    float m = -1e30f;
#pragma unroll
    for (int i = 0; i < 16; ++i) m = fmaxf(m, v[i]);
#pragma unroll
    for (int off = 32; off > 0; off >>= 1)
        m = fmaxf(m, __shfl_xor(m, off, 64));

    // ---- pass 2: e_i = exp((x_i - m)/T), s = sum e_i (overwrite v[] with e) ----
    float s = 0.f;
#pragma unroll
    for (int i = 0; i < 16; ++i) {
        float e = __expf((v[i] - m) * TEMP_INV);   // padded lanes -> exp(-huge) = 0
        v[i] = e;
        s += e;
    }
#pragma unroll
    for (int off = 32; off > 0; off >>= 1)
        s += __shfl_xor(s, off, 64);

    const int   t     = teacher[row];      // broadcast within wave -> 1 txn
    const float w     = weight[t];         // 4 KB table, L1/L2 resident
    const float inv_s = 1.0f / s;

    // ---- pass 3: S = sum_i log(1 - p_i + eps); also pick out p_t ----
    float S = 0.f, pt = 0.f;
#pragma unroll
    for (int it = 0; it < 4; ++it) {
#pragma unroll
        for (int k = 0; k < 4; ++k) {
            const int e_idx = (it * 64 + lane) * 4 + k;
            if (e_idx < C_CLASSES) {
                const float p = v[it*4+k] * inv_s;
                S += __logf(1.0f - p + FCE_EPS);   // matches ref op order in f32
                if (e_idx == t) pt = p;
            }
        }
    }
#pragma unroll
    for (int off = 32; off > 0; off >>= 1) {
        S  += __shfl_xor(S,  off, 64);
        pt += __shfl_xor(pt, off, 64);
    }

    if (lane == 0) {
        // loss = -log(p_t+eps) - w * (S - log(1-p_t+eps))   [t-term excluded]
        const float loss = -__logf(pt + FCE_EPS)
                         - w * (S - __logf(1.0f - pt + FCE_EPS));
        out[row] = loss;
    }
}

extern "C" void kernel_launch(void* const* d_in, const int* in_sizes, int n_in,
                              void* d_out, int out_size, void* d_ws, size_t ws_size,
                              hipStream_t stream) {
    const float* pred    = (const float*)d_in[0];
    const float* weight  = (const float*)d_in[1];
    const int*   teacher = (const int*)d_in[2];
    float*       out     = (float*)d_out;

    const int B = in_sizes[2];                 // 65536 rows
    const int grid = (B + 3) / 4;              // 4 rows (waves) per 256-thr block
    fce_kernel<<<grid, 256, 0, stream>>>(pred, weight, teacher, out, B);
}

// Round 2
// 346.819 us; speedup vs baseline: 1.0007x; 1.0007x over previous
//
#include <hip/hip_runtime.h>

// FCE loss: per-row softmax(pred/T) over C=1000, then
// loss[j] = -log(p_t + eps) - w_t * sum_{c != t} log(1 - p_c + eps)
//
// One 64-lane wave per row; 16 f32/lane in registers -> pred read from HBM
// exactly once. Row = 4000 B, float4 loads coalesce (1 KiB/wave-instr).
//
// Numerics: exp in exp2-domain with fused constant k = (1/T)*log2(e);
// sum of logs accumulated in log2-domain, scaled by ln2 once per row.
// Pad lanes (24 elements) contribute log(1+eps) ~= 1e-7 each to S
// (2.4e-6 total) -- negligible vs the 0.175 absmax threshold, so pass 3
// has no per-element branches at all. p_t is recomputed from a single
// reload of pred[row*C + t] (wave-uniform, cache-hot) with the identical
// exp2 formula, so the t-term subtraction is bit-consistent.

#define C_CLASSES 1000
#define K_EXP2    0.36067376022224085f   // (1/TEMP) * log2(e), TEMP = 4
#define LN2F      0.69314718055994531f
#define FCE_EPS   1e-7f

__global__ __launch_bounds__(256) void fce_kernel(
    const float* __restrict__ pred,
    const float* __restrict__ weight,
    const int*   __restrict__ teacher,
    float*       __restrict__ out,
    int B)
{
    const int lane = threadIdx.x & 63;
    const int wave = threadIdx.x >> 6;
    const int row  = blockIdx.x * 4 + wave;
    if (row >= B) return;

    const float* rp = pred + (size_t)row * C_CLASSES;

    // ---- load entire row: 4 x float4 per lane (250 real float4s + pad) ----
    float v[16];
#pragma unroll
    for (int it = 0; it < 4; ++it) {
        const int idx4 = it * 64 + lane;
        if (idx4 < C_CLASSES / 4) {
            float4 f = ((const float4*)rp)[idx4];
            v[it*4+0] = f.x; v[it*4+1] = f.y; v[it*4+2] = f.z; v[it*4+3] = f.w;
        } else {
            v[it*4+0] = v[it*4+1] = v[it*4+2] = v[it*4+3] = -1e30f; // exp2 -> 0
        }
    }

    // ---- row max ----
    float m = -1e30f;
#pragma unroll
    for (int i = 0; i < 16; ++i) m = fmaxf(m, v[i]);
#pragma unroll
    for (int off = 32; off > 0; off >>= 1)
        m = fmaxf(m, __shfl_xor(m, off, 64));

    // ---- e_i = exp2(x_i*k - m*k), s = sum e_i ----
    const float mk = m * K_EXP2;
    float s = 0.f;
#pragma unroll
    for (int i = 0; i < 16; ++i) {
        float e = __builtin_exp2f(__builtin_fmaf(v[i], K_EXP2, -mk));
        v[i] = e;
        s += e;
    }
#pragma unroll
    for (int off = 32; off > 0; off >>= 1)
        s += __shfl_xor(s, off, 64);

    const int   t     = teacher[row];          // wave-uniform -> 1 txn
    const float w     = weight[t];             // 4 KB table, cache-resident
    const float xt    = rp[t];                 // wave-uniform reload, L1/L2 hot
    const float inv_s = 1.0f / s;

    // ---- S2 = sum_i log2(1 - p_i + eps), branch-free over all 1024 slots ----
    float S2 = 0.f;
#pragma unroll
    for (int i = 0; i < 16; ++i) {
        const float p = v[i] * inv_s;
        S2 += __log2f(1.0f - p + FCE_EPS);
    }
#pragma unroll
    for (int off = 32; off > 0; off >>= 1)
        S2 += __shfl_xor(S2, off, 64);

    if (lane == 0) {
        const float pt   = __builtin_exp2f(__builtin_fmaf(xt, K_EXP2, -mk)) * inv_s;
        const float loss = -__logf(pt + FCE_EPS)
                         - w * (S2 * LN2F - __logf(1.0f - pt + FCE_EPS));
        out[row] = loss;
    }
}

extern "C" void kernel_launch(void* const* d_in, const int* in_sizes, int n_in,
                              void* d_out, int out_size, void* d_ws, size_t ws_size,
                              hipStream_t stream) {
    const float* pred    = (const float*)d_in[0];
    const float* weight  = (const float*)d_in[1];
    const int*   teacher = (const int*)d_in[2];
    float*       out     = (float*)d_out;

    const int B = in_sizes[2];                 // 65536 rows
    const int grid = (B + 3) / 4;              // 4 rows (waves) per 256-thr block
    fce_kernel<<<grid, 256, 0, stream>>>(pred, weight, teacher, out, B);
}